// Round 1
// baseline (2536.129 us; speedup 1.0000x reference)
//
#include <hip/hip_runtime.h>
#include <math.h>

#define N_NODES 20000
#define N_EDGES 320000
#define TOT_E   340000      // E + N self loops
#define IN_F    512
#define HC      512         // H*C
#define NHEAD   4
#define CHAN    128
#define NEG_SLOPE 0.2f
#define BN_EPS  1e-5f

// ---- float <-> ordered-uint encoding for atomicMax on floats ----
__device__ __forceinline__ unsigned enc_f(float f) {
  unsigned u = __float_as_uint(f);
  return (u & 0x80000000u) ? ~u : (u | 0x80000000u);
}
__device__ __forceinline__ float dec_f(unsigned k) {
  unsigned u = (k & 0x80000000u) ? (k ^ 0x80000000u) : ~k;
  return __uint_as_float(u);
}

// ---- column means (sums) of edge_attr [E,4] ----
__global__ void edge_mean_kernel(const float* __restrict__ EA, float* __restrict__ msum) {
  float s0 = 0.f, s1 = 0.f, s2 = 0.f, s3 = 0.f;
  for (int i = blockIdx.x * blockDim.x + threadIdx.x; i < N_EDGES;
       i += gridDim.x * blockDim.x) {
    const float4 v = *(const float4*)&EA[(size_t)i * 4];
    s0 += v.x; s1 += v.y; s2 += v.z; s3 += v.w;
  }
#pragma unroll
  for (int m = 32; m >= 1; m >>= 1) {
    s0 += __shfl_down(s0, m); s1 += __shfl_down(s1, m);
    s2 += __shfl_down(s2, m); s3 += __shfl_down(s3, m);
  }
  __shared__ float red[4][4];
  const int lane = threadIdx.x & 63, wid = threadIdx.x >> 6;
  if (lane == 0) { red[wid][0] = s0; red[wid][1] = s1; red[wid][2] = s2; red[wid][3] = s3; }
  __syncthreads();
  if (threadIdx.x < 4) {
    float v = red[0][threadIdx.x] + red[1][threadIdx.x] + red[2][threadIdx.x] + red[3][threadIdx.x];
    atomicAdd(&msum[threadIdx.x], v);
  }
}

// ---- q[d][h] = sum_c W_edge[d, h*C+c] * att_edge[h, c]  (4x4) ----
__global__ void qmat_kernel(const float* __restrict__ We, const float* __restrict__ aedg,
                            float* __restrict__ q) {
  const int d = blockIdx.x >> 2, h = blockIdx.x & 3, lane = threadIdx.x; // 64 threads
  const int base = h * CHAN + lane * 2;
  float v = We[d * HC + base] * aedg[base] + We[d * HC + base + 1] * aedg[base + 1];
#pragma unroll
  for (int m = 32; m >= 1; m >>= 1) v += __shfl_down(v, m);
  if (lane == 0) q[d * 4 + h] = v;
}

// ---- h = x @ W : (20000,512)x(512,512) f32, 128x128 tile, 8x8 microtile ----
__global__ __launch_bounds__(256) void gemm_h_kernel(const float* __restrict__ X,
                                                     const float* __restrict__ W,
                                                     float* __restrict__ Hout) {
  __shared__ float As[16][128];   // k-major (transposed A tile)
  __shared__ float Bs[16][128];
  const int tid = threadIdx.x;
  const int bm = blockIdx.x * 128;
  const int bn = blockIdx.y * 128;
  const int tm = (tid >> 4) << 3;        // 0..120
  const int tn = (tid & 15) << 3;        // 0..120
  const int ar = tid >> 1;               // 0..127
  const int ac = (tid & 1) << 3;         // 0 or 8
  const int br = tid >> 4;               // 0..15
  const int bc = (tid & 15) << 3;        // 0..120
  const int arow = bm + ar;
  float acc[8][8] = {};
  for (int k0 = 0; k0 < IN_F; k0 += 16) {
    float4 a0 = {0, 0, 0, 0}, a1 = {0, 0, 0, 0};
    if (arow < N_NODES) {
      a0 = *(const float4*)&X[(size_t)arow * IN_F + k0 + ac];
      a1 = *(const float4*)&X[(size_t)arow * IN_F + k0 + ac + 4];
    }
    const float4 b0 = *(const float4*)&W[(size_t)(k0 + br) * HC + bn + bc];
    const float4 b1 = *(const float4*)&W[(size_t)(k0 + br) * HC + bn + bc + 4];
    __syncthreads();
    As[ac + 0][ar] = a0.x; As[ac + 1][ar] = a0.y; As[ac + 2][ar] = a0.z; As[ac + 3][ar] = a0.w;
    As[ac + 4][ar] = a1.x; As[ac + 5][ar] = a1.y; As[ac + 6][ar] = a1.z; As[ac + 7][ar] = a1.w;
    *(float4*)&Bs[br][bc] = b0;
    *(float4*)&Bs[br][bc + 4] = b1;
    __syncthreads();
#pragma unroll
    for (int k = 0; k < 16; ++k) {
      float a[8], b[8];
      *(float4*)&a[0] = *(const float4*)&As[k][tm];
      *(float4*)&a[4] = *(const float4*)&As[k][tm + 4];
      *(float4*)&b[0] = *(const float4*)&Bs[k][tn];
      *(float4*)&b[4] = *(const float4*)&Bs[k][tn + 4];
#pragma unroll
      for (int i = 0; i < 8; ++i)
#pragma unroll
        for (int j = 0; j < 8; ++j) acc[i][j] += a[i] * b[j];
    }
  }
#pragma unroll
  for (int i = 0; i < 8; ++i) {
    const int row = bm + tm + i;
    if (row < N_NODES) {
      float4 v0 = {acc[i][0], acc[i][1], acc[i][2], acc[i][3]};
      float4 v1 = {acc[i][4], acc[i][5], acc[i][6], acc[i][7]};
      *(float4*)&Hout[(size_t)row * HC + bn + tn] = v0;
      *(float4*)&Hout[(size_t)row * HC + bn + tn + 4] = v1;
    }
  }
}

// ---- per-node head dots: a_src/a_dst [N,4]; one wave per node ----
__global__ void node_att_kernel(const float* __restrict__ Hm,
                                const float* __restrict__ att_s,
                                const float* __restrict__ att_d,
                                float* __restrict__ a_src, float* __restrict__ a_dst) {
  const int n = blockIdx.x * 4 + (threadIdx.x >> 6);  // 4 waves/block, exact 20000
  const int lane = threadIdx.x & 63;
  const int j = lane * 8;                              // head = lane>>4 (128ch = 16 lanes)
  const float4 h0 = *(const float4*)&Hm[(size_t)n * HC + j];
  const float4 h1 = *(const float4*)&Hm[(size_t)n * HC + j + 4];
  const float4 s0 = *(const float4*)&att_s[j];
  const float4 s1 = *(const float4*)&att_s[j + 4];
  const float4 d0 = *(const float4*)&att_d[j];
  const float4 d1 = *(const float4*)&att_d[j + 4];
  float s = h0.x * s0.x + h0.y * s0.y + h0.z * s0.z + h0.w * s0.w +
            h1.x * s1.x + h1.y * s1.y + h1.z * s1.z + h1.w * s1.w;
  float d = h0.x * d0.x + h0.y * d0.y + h0.z * d0.z + h0.w * d0.w +
            h1.x * d1.x + h1.y * d1.y + h1.z * d1.z + h1.w * d1.w;
#pragma unroll
  for (int m = 8; m >= 1; m >>= 1) { s += __shfl_xor(s, m); d += __shfl_xor(d, m); }
  if ((lane & 15) == 0) {
    const int h = lane >> 4;
    a_src[n * 4 + h] = s;
    a_dst[n * 4 + h] = d;
  }
}

// ---- per-edge alpha (leaky-relu'd) + segment max via atomicMax ----
__global__ void alpha_kernel(const int* __restrict__ EI, const float* __restrict__ EA,
                             const float* __restrict__ a_src, const float* __restrict__ a_dst,
                             const float* __restrict__ msum, const float* __restrict__ q,
                             float* __restrict__ alpha, unsigned* __restrict__ amax) {
  const int k = blockIdx.x * blockDim.x + threadIdx.x;
  if (k >= TOT_E) return;
  int s, d;
  float e0, e1, e2, e3;
  if (k < N_EDGES) {
    s = EI[k]; d = EI[N_EDGES + k];
    const float4 e = *(const float4*)&EA[(size_t)k * 4];
    e0 = e.x; e1 = e.y; e2 = e.z; e3 = e.w;
  } else {
    s = d = k - N_EDGES;
    const float inv = 1.0f / (float)N_EDGES;
    e0 = msum[0] * inv; e1 = msum[1] * inv; e2 = msum[2] * inv; e3 = msum[3] * inv;
  }
  const float4 as = *(const float4*)&a_src[s * 4];
  const float4 ad = *(const float4*)&a_dst[d * 4];
  float al[4];
  const float asv[4] = {as.x, as.y, as.z, as.w};
  const float adv[4] = {ad.x, ad.y, ad.z, ad.w};
#pragma unroll
  for (int h = 0; h < 4; ++h) {
    float ae = e0 * q[h] + e1 * q[4 + h] + e2 * q[8 + h] + e3 * q[12 + h];
    float a = asv[h] + adv[h] + ae;
    a = (a >= 0.f) ? a : NEG_SLOPE * a;
    al[h] = a;
    atomicMax(&amax[d * 4 + h], enc_f(a));
  }
  float4 o = {al[0], al[1], al[2], al[3]};
  *(float4*)&alpha[(size_t)k * 4] = o;
}

// ---- ex = exp(alpha - amax[dst]); denom[dst] += ex ----
__global__ void exp_kernel(const int* __restrict__ EI, float* __restrict__ alpha,
                           const unsigned* __restrict__ amax, float* __restrict__ denom) {
  const int k = blockIdx.x * blockDim.x + threadIdx.x;
  if (k >= TOT_E) return;
  const int d = (k < N_EDGES) ? EI[N_EDGES + k] : (k - N_EDGES);
  float4 al = *(const float4*)&alpha[(size_t)k * 4];
  const float m0 = dec_f(amax[d * 4 + 0]);
  const float m1 = dec_f(amax[d * 4 + 1]);
  const float m2 = dec_f(amax[d * 4 + 2]);
  const float m3 = dec_f(amax[d * 4 + 3]);
  al.x = expf(al.x - m0); al.y = expf(al.y - m1);
  al.z = expf(al.z - m2); al.w = expf(al.w - m3);
  *(float4*)&alpha[(size_t)k * 4] = al;
  atomicAdd(&denom[d * 4 + 0], al.x);
  atomicAdd(&denom[d * 4 + 1], al.y);
  atomicAdd(&denom[d * 4 + 2], al.z);
  atomicAdd(&denom[d * 4 + 3], al.w);
}

// ---- initialize out with the self-loop message (covers every element) ----
__global__ __launch_bounds__(128) void selfloop_kernel(const float* __restrict__ Hm,
                                                       const float* __restrict__ alpha,
                                                       const float* __restrict__ denom,
                                                       float* __restrict__ out) {
  const int n = blockIdx.x;
  const int t = threadIdx.x;          // 128 threads -> 4 floats each
  const int head = t >> 5;
  const float w = alpha[(size_t)(N_EDGES + n) * 4 + head] / (denom[n * 4 + head] + 1e-16f);
  const float4 hv = *(const float4*)&Hm[(size_t)n * HC + t * 4];
  float4 o = {hv.x * w, hv.y * w, hv.z * w, hv.w * w};
  *(float4*)&out[(size_t)n * HC + t * 4] = o;
}

// ---- accumulate real-edge messages with float atomics ----
__global__ __launch_bounds__(128) void aggregate_kernel(const int* __restrict__ EI,
                                                        const float* __restrict__ Hm,
                                                        const float* __restrict__ alpha,
                                                        const float* __restrict__ denom,
                                                        float* __restrict__ out) {
  __shared__ float w4[4];
  __shared__ int ss[2];
  const int e = blockIdx.x;
  const int t = threadIdx.x;          // 128
  if (t < 4) {
    const int d = EI[N_EDGES + e];
    w4[t] = alpha[(size_t)e * 4 + t] / (denom[d * 4 + t] + 1e-16f);
    if (t == 0) { ss[0] = EI[e]; ss[1] = d; }
  }
  __syncthreads();
  const int s = ss[0], d = ss[1];
  const float w = w4[t >> 5];
  const float4 hv = *(const float4*)&Hm[(size_t)s * HC + t * 4];
  float* op = &out[(size_t)d * HC + t * 4];
  atomicAdd(op + 0, hv.x * w);
  atomicAdd(op + 1, hv.y * w);
  atomicAdd(op + 2, hv.z * w);
  atomicAdd(op + 3, hv.w * w);
}

// ---- BN column sums / sums of squares ----
__global__ void bn_stats_kernel(const float* __restrict__ out,
                                float* __restrict__ colsum, float* __restrict__ colsq) {
  const int t = threadIdx.x;          // 256 threads -> 2 channels each
  const int j = t * 2;
  float s0 = 0.f, s1 = 0.f, q0 = 0.f, q1 = 0.f;
  for (int r = blockIdx.x; r < N_NODES; r += gridDim.x) {
    const float2 v = *(const float2*)&out[(size_t)r * HC + j];
    s0 += v.x; s1 += v.y; q0 += v.x * v.x; q1 += v.y * v.y;
  }
  atomicAdd(&colsum[j], s0);
  atomicAdd(&colsum[j + 1], s1);
  atomicAdd(&colsq[j], q0);
  atomicAdd(&colsq[j + 1], q1);
}

// ---- fold BN into per-channel scale/shift (bias cancels exactly) ----
__global__ void bn_finalize_kernel(const float* __restrict__ colsum, const float* __restrict__ colsq,
                                   const float* __restrict__ gamma, const float* __restrict__ beta,
                                   float* __restrict__ scale, float* __restrict__ shift) {
  const int j = threadIdx.x;
  const float mu = colsum[j] * (1.0f / N_NODES);
  const float var = colsq[j] * (1.0f / N_NODES) - mu * mu;
  const float sc = gamma[j] * rsqrtf(var + BN_EPS);
  scale[j] = sc;
  shift[j] = beta[j] - mu * sc;
}

__global__ void bn_apply_kernel(float* __restrict__ out, const float* __restrict__ scale,
                                const float* __restrict__ shift) {
  const int i = blockIdx.x * blockDim.x + threadIdx.x;   // float4 index
  if (i >= N_NODES * HC / 4) return;
  const int j4 = (i & (HC / 4 - 1)) * 4;
  float4 v = ((const float4*)out)[i];
  const float4 sc = *(const float4*)&scale[j4];
  const float4 sh = *(const float4*)&shift[j4];
  v.x = v.x * sc.x + sh.x; v.y = v.y * sc.y + sh.y;
  v.z = v.z * sc.z + sh.z; v.w = v.w * sc.w + sh.w;
  ((float4*)out)[i] = v;
}

extern "C" void kernel_launch(void* const* d_in, const int* in_sizes, int n_in,
                              void* d_out, int out_size, void* d_ws, size_t ws_size,
                              hipStream_t stream) {
  const float* x     = (const float*)d_in[0];
  const int*   ei    = (const int*)d_in[1];
  const float* ea    = (const float*)d_in[2];
  const float* W     = (const float*)d_in[3];
  const float* We    = (const float*)d_in[4];
  const float* att_s = (const float*)d_in[5];
  const float* att_d = (const float*)d_in[6];
  const float* att_e = (const float*)d_in[7];
  // d_in[8] = bias: cancels exactly in BatchNorm -> unused
  const float* gamma = (const float*)d_in[9];
  const float* beta  = (const float*)d_in[10];
  float* out = (float*)d_out;
  float* ws  = (float*)d_ws;

  // workspace layout (floats)
  float*    h_buf  = ws;                                   // N*512
  float*    a_src  = h_buf + (size_t)N_NODES * HC;         // N*4
  float*    a_dst  = a_src + N_NODES * NHEAD;              // N*4
  float*    alpha  = a_dst + N_NODES * NHEAD;              // TOT_E*4
  float*    denom  = alpha + (size_t)TOT_E * NHEAD;        // N*4   (zeroed)
  unsigned* amax   = (unsigned*)(denom + N_NODES * NHEAD); // N*4   (zeroed; 0 == -inf key)
  float*    msum   = (float*)(amax + N_NODES * NHEAD);     // 4     (zeroed)
  float*    colsum = msum + 4;                             // 512   (zeroed)
  float*    colsq  = colsum + HC;                          // 512   (zeroed)
  float*    qm     = colsq + HC;                           // 16
  float*    scale  = qm + 16;                              // 512
  float*    shift  = scale + HC;                           // 512

  // re-zero all accumulators every call (inside the captured graph)
  const size_t zero_bytes = (size_t)(N_NODES * NHEAD * 2 + 4 + HC * 2) * sizeof(float);
  hipMemsetAsync(denom, 0, zero_bytes, stream);

  edge_mean_kernel<<<256, 256, 0, stream>>>(ea, msum);
  qmat_kernel<<<16, 64, 0, stream>>>(We, att_e, qm);
  gemm_h_kernel<<<dim3((N_NODES + 127) / 128, HC / 128), 256, 0, stream>>>(x, W, h_buf);
  node_att_kernel<<<N_NODES / 4, 256, 0, stream>>>(h_buf, att_s, att_d, a_src, a_dst);
  alpha_kernel<<<(TOT_E + 255) / 256, 256, 0, stream>>>(ei, ea, a_src, a_dst, msum, qm, alpha, amax);
  exp_kernel<<<(TOT_E + 255) / 256, 256, 0, stream>>>(ei, alpha, amax, denom);
  selfloop_kernel<<<N_NODES, 128, 0, stream>>>(h_buf, alpha, denom, out);
  aggregate_kernel<<<N_EDGES, 128, 0, stream>>>(ei, h_buf, alpha, denom, out);
  bn_stats_kernel<<<256, 256, 0, stream>>>(out, colsum, colsq);
  bn_finalize_kernel<<<1, HC, 0, stream>>>(colsum, colsq, gamma, beta, scale, shift);
  bn_apply_kernel<<<(N_NODES * HC / 4 + 255) / 256, 256, 0, stream>>>(out, scale, shift);
}